// Round 2
// baseline (472.693 us; speedup 1.0000x reference)
//
#include <hip/hip_runtime.h>
#include <hip/hip_bf16.h>

// Problem constants
#define VN 10000
#define HID 128
// W1 rows (161 x 128): [0,64) Wh, [64,128) Wm, 128 Wt, [129,161) Wp

using bf16x8 = __attribute__((ext_vector_type(8))) __bf16;
using f32x4  = __attribute__((ext_vector_type(4))) float;

// ---------------------------------------------------------------------------
// prep_kernel:
//   blocks [0,625): base[v][h] = b1[h] + h_t[v]@Wh + theta[v]@Wp   (fp32)
//   blocks [625,657): wmt[n*64+d] = bf16(Wm[d][n])  (transposed, n-major)
// ---------------------------------------------------------------------------
__global__ __launch_bounds__(256) void prep_kernel(
    const float* __restrict__ h_t, const float* __restrict__ theta,
    const float* __restrict__ W1, const float* __restrict__ b1,
    float* __restrict__ base, __bf16* __restrict__ wmt)
{
  const int blk = blockIdx.x;
  const int tid = threadIdx.x;
  if (blk < 625) {
    __shared__ float in[16][96];   // 16 nodes x (64 h_t | 32 theta)
    const int v0 = blk * 16;
    {
      const float4* src = (const float4*)(h_t + (size_t)v0 * 64);
      float4 f = src[tid];
      int vl = tid >> 4, c = (tid & 15) * 4;
      in[vl][c] = f.x; in[vl][c + 1] = f.y; in[vl][c + 2] = f.z; in[vl][c + 3] = f.w;
    }
    if (tid < 128) {
      const float4* src = (const float4*)(theta + (size_t)v0 * 32);
      float4 f = src[tid];
      int vl = tid >> 3, c = 64 + (tid & 7) * 4;
      in[vl][c] = f.x; in[vl][c + 1] = f.y; in[vl][c + 2] = f.z; in[vl][c + 3] = f.w;
    }
    __syncthreads();
    const int h = tid & 127;
    const int half = tid >> 7;      // wave-uniform
    float acc[8];
    const float bb = b1[h];
    #pragma unroll
    for (int k = 0; k < 8; k++) acc[k] = bb;
    #pragma unroll 8
    for (int d = 0; d < 64; d++) {
      float w = W1[d * 128 + h];                 // Wh row d
      #pragma unroll
      for (int k = 0; k < 8; k++) acc[k] += in[2 * k + half][d] * w;
    }
    #pragma unroll 8
    for (int d = 0; d < 32; d++) {
      float w = W1[(129 + d) * 128 + h];         // Wp row d
      #pragma unroll
      for (int k = 0; k < 8; k++) acc[k] += in[2 * k + half][64 + d] * w;
    }
    #pragma unroll
    for (int k = 0; k < 8; k++)
      base[(size_t)(v0 + 2 * k + half) * 128 + h] = acc[k];
  } else {
    int j = (blk - 625) * 256 + tid;   // 32 blocks * 256 = 8192 exact
    int n = j >> 6, d = j & 63;
    wmt[j] = (__bf16)W1[(64 + d) * 128 + n];     // Wm^T[n][d]
  }
}

// ---------------------------------------------------------------------------
// main_kernel: one block per node v (grid = 10000, 256 threads = 4 waves)
// No LDS staging: A fragments (messages) loaded straight to registers in the
// MFMA A-layout (A[m=lane&15][k=quad*8+j]); B fragments read from wmt (16 KB,
// L1-resident). No barriers until the tiny lOut store.
// ---------------------------------------------------------------------------
__global__ __launch_bounds__(256, 3) void main_kernel(
    const float* __restrict__ messages, const float* __restrict__ tau,
    const float* __restrict__ W1, const float* __restrict__ W2,
    const float* __restrict__ b2, const float* __restrict__ base,
    const __bf16* __restrict__ wmt, float* __restrict__ out)
{
  __shared__ float lOut[128];

  const int v = blockIdx.x;
  const int tid = threadIdx.x;
  const int w = tid >> 6;
  const int lane = tid & 63;
  const int quad = lane >> 4;
  const int l16 = lane & 15;

  // ---- A loads: each lane grabs its own fragments (32B-aligned, coalesced)
  const float* msg = messages + (size_t)v * 8192;
  float4 araw[2][2][2];                // [mt][ks][half-of-8-floats]
  #pragma unroll
  for (int mt = 0; mt < 2; mt++) {
    #pragma unroll
    for (int ks = 0; ks < 2; ks++) {
      const int m = 32 * w + mt * 16 + l16;
      const float4* p = (const float4*)(msg + m * 64 + ks * 32 + quad * 8);
      araw[mt][ks][0] = p[0];
      araw[mt][ks][1] = p[1];
    }
  }

  // ---- epilogue constants issued early (L1/L2 hits) ----
  float bb[8], w2[8], wt[8];
  #pragma unroll
  for (int nt = 0; nt < 8; nt++) {
    const int n = nt * 16 + l16;
    bb[nt] = base[(size_t)v * 128 + n];
    w2[nt] = W2[n];
    wt[nt] = W1[128 * 128 + n];        // Wt row
  }
  float tv[2];
  tv[0] = tau[2 * w];
  tv[1] = tau[2 * w + 1];
  const float b2v = b2[0];

  f32x4 acc[2][8];
  #pragma unroll
  for (int mt = 0; mt < 2; mt++)
    #pragma unroll
    for (int nt = 0; nt < 8; nt++) acc[mt][nt] = (f32x4){0.f, 0.f, 0.f, 0.f};

  #pragma unroll
  for (int ks = 0; ks < 2; ks++) {
    bf16x8 b[8];
    #pragma unroll
    for (int nt = 0; nt < 8; nt++)
      b[nt] = *(const bf16x8*)&wmt[(nt * 16 + l16) * 64 + ks * 32 + quad * 8];
    #pragma unroll
    for (int mt = 0; mt < 2; mt++) {
      const float* af = (const float*)&araw[mt][ks][0];
      bf16x8 a;
      #pragma unroll
      for (int j = 0; j < 8; j++) a[j] = (__bf16)af[j];
      #pragma unroll
      for (int nt = 0; nt < 8; nt++)
        acc[mt][nt] = __builtin_amdgcn_mfma_f32_16x16x32_bf16(a, b[nt], acc[mt][nt], 0, 0, 0);
    }
  }

  // ---- epilogue: + base + tau*Wt, relu, @W2, reduce over n ----
  #pragma unroll
  for (int mt = 0; mt < 2; mt++) {
    float ps[4] = {0.f, 0.f, 0.f, 0.f};
    #pragma unroll
    for (int nt = 0; nt < 8; nt++) {
      const float add = bb[nt] + tv[mt] * wt[nt];
      f32x4 a4 = acc[mt][nt];
      #pragma unroll
      for (int r = 0; r < 4; r++) {
        float hdn = fmaxf(a4[r] + add, 0.f);
        ps[r] += hdn * w2[nt];
      }
    }
    // sum across the 16 lanes sharing a quad (xor masks < 16 stay in-group)
    #pragma unroll
    for (int off = 1; off < 16; off <<= 1)
      #pragma unroll
      for (int r = 0; r < 4; r++) ps[r] += __shfl_xor(ps[r], off, 64);
    if (l16 == 0) {
      #pragma unroll
      for (int r = 0; r < 4; r++)
        lOut[32 * w + mt * 16 + quad * 4 + r] = ps[r];
    }
  }
  __syncthreads();
  if (tid < 128) out[(size_t)v * 128 + tid] = lOut[tid] + b2v;
}

// ---------------------------------------------------------------------------
extern "C" void kernel_launch(void* const* d_in, const int* in_sizes, int n_in,
                              void* d_out, int out_size, void* d_ws, size_t ws_size,
                              hipStream_t stream) {
  const float* h_t      = (const float*)d_in[0];
  const float* messages = (const float*)d_in[1];
  const float* tau      = (const float*)d_in[2];
  const float* theta    = (const float*)d_in[3];
  const float* W1       = (const float*)d_in[4];
  const float* b1       = (const float*)d_in[5];
  const float* W2       = (const float*)d_in[6];
  const float* b2       = (const float*)d_in[7];
  float* out = (float*)d_out;

  // ws layout: [0, VN*128) f32 base | 8192 bf16 Wm^T
  float* base = (float*)d_ws;
  __bf16* wmt = (__bf16*)((char*)d_ws + (size_t)VN * HID * sizeof(float));

  prep_kernel<<<625 + 32, 256, 0, stream>>>(h_t, theta, W1, b1, base, wmt);
  main_kernel<<<VN, 256, 0, stream>>>(messages, tau, W1, W2, b2, base, wmt, out);
}

// Round 3
// 452.850 us; speedup vs baseline: 1.0438x; 1.0438x over previous
//
#include <hip/hip_runtime.h>
#include <hip/hip_bf16.h>

// Problem constants
#define VN 10000
#define HID 128
// W1 rows (161 x 128): [0,64) Wh, [64,128) Wm, 128 Wt, [129,161) Wp

using bf16x8 = __attribute__((ext_vector_type(8))) __bf16;
using f32x4  = __attribute__((ext_vector_type(4))) float;

typedef const __attribute__((address_space(1))) uint32_t gbl_u32;
typedef __attribute__((address_space(3))) uint32_t lds_u32;

// ---------------------------------------------------------------------------
// prep_kernel:
//   blocks [0,625): base[v][h] = b1[h] + h_t[v]@Wh + theta[v]@Wp   (fp32)
//   blocks [625,657): wmt[n*64+d] = bf16(Wm[d][n])  (transposed, n-major)
// ---------------------------------------------------------------------------
__global__ __launch_bounds__(256) void prep_kernel(
    const float* __restrict__ h_t, const float* __restrict__ theta,
    const float* __restrict__ W1, const float* __restrict__ b1,
    float* __restrict__ base, __bf16* __restrict__ wmt)
{
  const int blk = blockIdx.x;
  const int tid = threadIdx.x;
  if (blk < 625) {
    __shared__ __align__(16) float in[16][96];   // 16 nodes x (64 h_t | 32 theta)
    const int v0 = blk * 16;
    {
      const float4* src = (const float4*)(h_t + (size_t)v0 * 64);
      float4 f = src[tid];
      int vl = tid >> 4, c = (tid & 15) * 4;
      *(float4*)&in[vl][c] = f;
    }
    if (tid < 128) {
      const float4* src = (const float4*)(theta + (size_t)v0 * 32);
      float4 f = src[tid];
      int vl = tid >> 3, c = 64 + (tid & 7) * 4;
      *(float4*)&in[vl][c] = f;
    }
    __syncthreads();
    const int h = tid & 127;
    const int half = tid >> 7;      // wave-uniform
    float acc[8];
    const float bb = b1[h];
    #pragma unroll
    for (int k = 0; k < 8; k++) acc[k] = bb;
    // Wh rows 0..64 : chunks of 4 d, float4 LDS broadcast reads
    #pragma unroll 4
    for (int dc = 0; dc < 16; dc++) {
      const int d = 4 * dc;
      float w0 = W1[(d + 0) * 128 + h];
      float w1 = W1[(d + 1) * 128 + h];
      float w2 = W1[(d + 2) * 128 + h];
      float w3 = W1[(d + 3) * 128 + h];
      #pragma unroll
      for (int k = 0; k < 8; k++) {
        float4 iv = *(const float4*)&in[2 * k + half][d];
        acc[k] += iv.x * w0 + iv.y * w1 + iv.z * w2 + iv.w * w3;
      }
    }
    // Wp rows 129..161 : theta part (cols 64..96 of in)
    #pragma unroll 4
    for (int dc = 0; dc < 8; dc++) {
      const int d = 4 * dc;
      float w0 = W1[(129 + d + 0) * 128 + h];
      float w1 = W1[(129 + d + 1) * 128 + h];
      float w2 = W1[(129 + d + 2) * 128 + h];
      float w3 = W1[(129 + d + 3) * 128 + h];
      #pragma unroll
      for (int k = 0; k < 8; k++) {
        float4 iv = *(const float4*)&in[2 * k + half][64 + d];
        acc[k] += iv.x * w0 + iv.y * w1 + iv.z * w2 + iv.w * w3;
      }
    }
    #pragma unroll
    for (int k = 0; k < 8; k++)
      base[(size_t)(v0 + 2 * k + half) * 128 + h] = acc[k];
  } else {
    int j = (blk - 625) * 256 + tid;   // 32 blocks * 256 = 8192 exact
    int n = j >> 6, d = j & 63;
    wmt[j] = (__bf16)W1[(64 + d) * 128 + n];     // Wm^T[n][d]
  }
}

// ---------------------------------------------------------------------------
// main_kernel: one block per node v (grid = 10000, 256 threads = 4 waves)
//   A (messages[v], 128x64 f32) staged via global_load_lds width=16 into
//   per-wave chunked LDS (8 x 1040 B per wave: 1 KB data + 16 B pad so
//   fragment ds_read_b128s rotate banks -> 2-way max = free).
//   B (Wm^T bf16) staged to LDS by all threads. ONE barrier total.
// ---------------------------------------------------------------------------
__global__ __launch_bounds__(256, 3) void main_kernel(
    const float* __restrict__ messages, const float* __restrict__ tau,
    const float* __restrict__ W1, const float* __restrict__ W2,
    const float* __restrict__ b2, const float* __restrict__ base,
    const __bf16* __restrict__ wmt, float* __restrict__ out)
{
  // layout: [0, 33280) A: wave w at w*8320, chunk j at +j*1040 (4 rows fp32)
  //         [33280, 51712) B bf16 128 rows x 72 (pad 64->72)
  //         [51712, ...) lOut
  __shared__ __align__(16) unsigned char lds[33280 + 18432 + 512];
  __bf16* lB = (__bf16*)(lds + 33280);
  float* lOut = (float*)(lds + 33280 + 18432);

  const int v = blockIdx.x;
  const int tid = threadIdx.x;
  const int w = tid >> 6;
  const int lane = tid & 63;
  const int quad = lane >> 4;
  const int l16 = lane & 15;

  const float* msg = messages + (size_t)v * 8192;

  // ---- B loads to VGPR first (oldest in vmcnt queue) ----
  uint4 breg[4];
  {
    const uint4* bsrc = (const uint4*)wmt;
    #pragma unroll
    for (int j = 0; j < 4; j++) breg[j] = bsrc[j * 256 + tid];
  }

  // ---- A: async global->LDS, 8 chunks x 1 KB per wave (own rows only) ----
  #pragma unroll
  for (int j = 0; j < 8; j++) {
    const float* g = msg + (32 * w + 4 * j) * 64 + lane * 4;  // lane*16 B
    __builtin_amdgcn_global_load_lds((gbl_u32*)g,
                                     (lds_u32*)(lds + w * 8320 + j * 1040),
                                     16, 0, 0);
  }

  // ---- epilogue constants (issued before the barrier) ----
  float bb[8], w2v[8], wtv[8];
  #pragma unroll
  for (int nt = 0; nt < 8; nt++) {
    const int n = nt * 16 + l16;
    bb[nt]  = base[(size_t)v * 128 + n];
    w2v[nt] = W2[n];
    wtv[nt] = W1[128 * 128 + n];        // Wt row
  }
  float tv[2];
  tv[0] = tau[2 * w];
  tv[1] = tau[2 * w + 1];
  const float b2v = b2[0];

  // ---- B writes to LDS (waits only on breg loads) ----
  #pragma unroll
  for (int j = 0; j < 4; j++) {
    int idx = j * 256 + tid;
    int r = idx >> 3, c = (idx & 7) * 8;
    *(uint4*)&lB[r * 72 + c] = breg[j];
  }

  __syncthreads();   // drains vmcnt(0): A staged + B visible

  // ---- MFMA: wave w covers rows [32w, 32w+32), all 128 cols ----
  f32x4 acc[2][8];
  #pragma unroll
  for (int mt = 0; mt < 2; mt++)
    #pragma unroll
    for (int nt = 0; nt < 8; nt++) acc[mt][nt] = (f32x4){0.f, 0.f, 0.f, 0.f};

  #pragma unroll
  for (int ks = 0; ks < 2; ks++) {
    bf16x8 b[8];
    #pragma unroll
    for (int nt = 0; nt < 8; nt++)
      b[nt] = *(const bf16x8*)&lB[(nt * 16 + l16) * 72 + ks * 32 + quad * 8];
    #pragma unroll
    for (int mt = 0; mt < 2; mt++) {
      const int rr = mt * 16 + l16;
      const float4* ap = (const float4*)(lds + w * 8320 + (rr >> 2) * 1040 +
                                         (rr & 3) * 256 + (ks * 32 + quad * 8) * 4);
      float4 f0 = ap[0], f1 = ap[1];
      bf16x8 a;
      a[0] = (__bf16)f0.x; a[1] = (__bf16)f0.y; a[2] = (__bf16)f0.z; a[3] = (__bf16)f0.w;
      a[4] = (__bf16)f1.x; a[5] = (__bf16)f1.y; a[6] = (__bf16)f1.z; a[7] = (__bf16)f1.w;
      #pragma unroll
      for (int nt = 0; nt < 8; nt++)
        acc[mt][nt] = __builtin_amdgcn_mfma_f32_16x16x32_bf16(a, b[nt], acc[mt][nt], 0, 0, 0);
    }
  }

  // ---- epilogue: + base + tau*Wt, relu, @W2, reduce over n ----
  #pragma unroll
  for (int mt = 0; mt < 2; mt++) {
    float ps[4] = {0.f, 0.f, 0.f, 0.f};
    #pragma unroll
    for (int nt = 0; nt < 8; nt++) {
      const float add = bb[nt] + tv[mt] * wtv[nt];
      f32x4 a4 = acc[mt][nt];
      #pragma unroll
      for (int r = 0; r < 4; r++) {
        float hdn = fmaxf(a4[r] + add, 0.f);
        ps[r] += hdn * w2v[nt];
      }
    }
    // sum across the 16 lanes sharing a quad (xor masks < 16 stay in-group)
    #pragma unroll
    for (int off = 1; off < 16; off <<= 1)
      #pragma unroll
      for (int r = 0; r < 4; r++) ps[r] += __shfl_xor(ps[r], off, 64);
    if (l16 == 0) {
      #pragma unroll
      for (int r = 0; r < 4; r++)
        lOut[32 * w + mt * 16 + quad * 4 + r] = ps[r];
    }
  }
  __syncthreads();
  if (tid < 128) out[(size_t)v * 128 + tid] = lOut[tid] + b2v;
}

// ---------------------------------------------------------------------------
extern "C" void kernel_launch(void* const* d_in, const int* in_sizes, int n_in,
                              void* d_out, int out_size, void* d_ws, size_t ws_size,
                              hipStream_t stream) {
  const float* h_t      = (const float*)d_in[0];
  const float* messages = (const float*)d_in[1];
  const float* tau      = (const float*)d_in[2];
  const float* theta    = (const float*)d_in[3];
  const float* W1       = (const float*)d_in[4];
  const float* b1       = (const float*)d_in[5];
  const float* W2       = (const float*)d_in[6];
  const float* b2       = (const float*)d_in[7];
  float* out = (float*)d_out;

  // ws layout: [0, VN*128) f32 base | 8192 bf16 Wm^T
  float* base = (float*)d_ws;
  __bf16* wmt = (__bf16*)((char*)d_ws + (size_t)VN * HID * sizeof(float));

  prep_kernel<<<625 + 32, 256, 0, stream>>>(h_t, theta, W1, b1, base, wmt);
  main_kernel<<<VN, 256, 0, stream>>>(messages, tau, W1, W2, b2, base, wmt, out);
}